// Round 4
// baseline (138.484 us; speedup 1.0000x reference)
//
#include <hip/hip_runtime.h>
#include <hip/hip_fp16.h>

#define B_    4
#define C_    192
#define N_    8192
#define K_    16
#define O_    192
#define TWOC_ 384
#define BN_   (B_ * N_)

typedef __attribute__((ext_vector_type(8))) _Float16 half8;
typedef __attribute__((ext_vector_type(4))) _Float16 half4v;
typedef __attribute__((ext_vector_type(4))) float floatx4;
typedef __attribute__((ext_vector_type(4))) float fvec4;
typedef __attribute__((ext_vector_type(4))) int   ivec4;
typedef __attribute__((ext_vector_type(4))) unsigned int uvec4;

static __device__ __forceinline__ half8 shflx8(half8 v, int m) {
    union { half8 h; int i[4]; } u;
    u.h = v;
#pragma unroll
    for (int q = 0; q < 4; q++) u.i[q] = __shfl_xor(u.i[q], m, 64);
    return u.h;
}
static __device__ __forceinline__ half4v shflx4(half4v v, int m) {
    union { half4v h; int i[2]; } u;
    u.h = v;
#pragma unroll
    for (int q = 0; q < 2; q++) u.i[q] = __shfl_xor(u.i[q], m, 64);
    return u.h;
}

// ---------------- K1: prep = transpose x -> xt fp16  +  convert W -> fp16 ----------------
// blocks 0..6143: 32x32 transpose tiles (XCD-swizzled). blocks 6144..6161: W convert.
__global__ __launch_bounds__(256) void k_prep(const float* __restrict__ x,
                                              const float* __restrict__ W,
                                              unsigned short* __restrict__ xt,
                                              unsigned short* __restrict__ Wb) {
    int bid = blockIdx.x;
    int tid = threadIdx.x;

    if (bid >= 6144) {
        // W: 192*384 = 73728 fp32 -> fp16.  18 blocks x 256 thr x 16 elems.
        int base = ((bid - 6144) * 256 + tid) * 16;
        union { unsigned short u[16]; uvec4 v[2]; } o;
#pragma unroll
        for (int q = 0; q < 16; q += 4) {
            fvec4 f = __builtin_nontemporal_load((const fvec4*)(W + base + q));
            union { _Float16 h; unsigned short s; } c;
            c.h = (_Float16)f.x; o.u[q + 0] = c.s;
            c.h = (_Float16)f.y; o.u[q + 1] = c.s;
            c.h = (_Float16)f.z; o.u[q + 2] = c.s;
            c.h = (_Float16)f.w; o.u[q + 3] = c.s;
        }
        *(uvec4*)(Wb + base)     = o.v[0];
        *(uvec4*)(Wb + base + 8) = o.v[1];
        return;
    }

    __shared__ float tile[32][33];
    int xcd  = bid & 7;
    int b    = xcd >> 1;
    int half = xcd & 1;
    int slot = bid >> 3;                 // 0..767
    int ct   = slot >> 7;                // 0..5
    int nt   = half * 128 + (slot & 127);// 0..255
    int c0 = ct * 32, n0 = nt * 32;

    int cc  = tid >> 3;                  // 0..31
    int nn4 = (tid & 7) * 4;             // 0,4,..,28
    const float* xp = x + ((size_t)b * C_ + c0 + cc) * N_ + n0 + nn4;
    fvec4 v = __builtin_nontemporal_load((const fvec4*)xp);
    tile[nn4 + 0][cc] = v.x;
    tile[nn4 + 1][cc] = v.y;
    tile[nn4 + 2][cc] = v.z;
    tile[nn4 + 3][cc] = v.w;
    __syncthreads();

#pragma unroll
    for (int i = 0; i < 2; i++) {
        int id  = i * 256 + tid;         // 0..511
        int row = id >> 4;               // 0..31
        int ch2 = id & 15;               // 0..15
        union { _Float16 h[2]; unsigned int u; } p;
        p.h[0] = (_Float16)tile[row][ch2 * 2];
        p.h[1] = (_Float16)tile[row][ch2 * 2 + 1];
        *(unsigned int*)(xt + ((size_t)b * N_ + n0 + row) * C_ + c0 + ch2 * 2) = p.u;
    }
}

// ---------------- K2: fused max-rel gather + 1x1 conv ----------------
// 1024 blocks x 256 thr (4 waves); block = 32 nodes -> 4 blocks/CU, 16 waves/CU.
// Phase 1: gather (round-2 kg-split structure), rel -> 12 KiB swizzled LDS.
// Phase 2: GEMM, xs-half from global xt (L2/L3-hit), rel-half from LDS.
__global__ __launch_bounds__(256, 4) void k_fused(const unsigned short* __restrict__ xt,
                                                  const int* __restrict__ eidx,
                                                  const unsigned short* __restrict__ Wb,
                                                  const float* __restrict__ bias,
                                                  float* __restrict__ out) {
    __shared__ __align__(16) unsigned short rtile[32 * C_];   // 12 KiB
    __shared__ __align__(16) int sidx[32][36];                // 4.5 KiB (16B-aligned rows)
    char* rb0 = (char*)rtile;

    int bid  = blockIdx.x;               // 1024
    int xcd  = bid & 7;
    int b    = xcd >> 1;
    int slot = bid >> 3;                 // 0..127
    int n0   = ((xcd & 1) * 128 + slot) * 32;

    int tid  = threadIdx.x;
    int wave = tid >> 6;
    int lane = tid & 63;
    int m16  = lane & 15;
    int quad = lane >> 4;

    // ---- stage sidx: 32 nodes x {16 j, 16 i}; one nt int4 per thread ----
    {
        const int* e0 = eidx + ((size_t)b * N_ + n0) * K_;
        const int* e1 = e0 + (size_t)BN_ * K_;
        int side = tid >> 7;             // 0: e0(j), 1: e1(i)
        int id   = tid & 127;            // int4 index within side
        const int* src = side ? e1 : e0;
        ivec4 v = __builtin_nontemporal_load((const ivec4*)src + id);
        int node = id >> 2, kq = (id & 3) * 4;
        *(ivec4*)&sidx[node][side * 16 + kq] = v;
    }
    __syncthreads();

    // ---- gather: wave handles nodes [wave*8, wave*8+8) ----
    {
        int kg = quad, part = m16;
        const unsigned short* xb = xt + (size_t)b * N_ * C_;
#pragma unroll 2
        for (int nn = 0; nn < 8; nn++) {
            int node = wave * 8 + nn;
            ivec4 j4 = *(const ivec4*)&sidx[node][kg * 4];
            ivec4 i4 = *(const ivec4*)&sidx[node][16 + kg * 4];
            half8  m0;
            half4v m1;
#pragma unroll
            for (int it = 0; it < 4; it++) {
                int jn  = j4[it];
                int in_ = i4[it];
                const unsigned short* pj = xb + (size_t)jn * C_;
                const unsigned short* pi = xb + (size_t)in_ * C_;
                half8  a0 = *(const half8*)(pj + part * 8);
                half4v a1 = *(const half4v*)(pj + 128 + part * 4);
                half8  b0 = *(const half8*)(pi + part * 8);
                half4v b1 = *(const half4v*)(pi + 128 + part * 4);
                half8  d0 = a0 - b0;
                half4v d1 = a1 - b1;
                if (it == 0) { m0 = d0; m1 = d1; }
                else {
                    m0 = __builtin_elementwise_max(m0, d0);
                    m1 = __builtin_elementwise_max(m1, d1);
                }
            }
            m0 = __builtin_elementwise_max(m0, shflx8(m0, 16));
            m1 = __builtin_elementwise_max(m1, shflx4(m1, 16));
            m0 = __builtin_elementwise_max(m0, shflx8(m0, 32));
            m1 = __builtin_elementwise_max(m1, shflx4(m1, 32));

            if (kg == 0) {
                char* rb = rb0 + node * 384;
                unsigned int sw = (unsigned)(node & 7) << 4;
                *(half8*)(rb + ((unsigned)(part * 16) ^ sw))       = m0;
                *(half4v*)(rb + ((unsigned)(256 + part * 8) ^ sw)) = m1;
            }
        }
    }
    __syncthreads();

    // ---- GEMM: wave = o-block [wave*48, wave*48+48), n = 32 (2 tiles of 16) ----
    const unsigned short* wbase = Wb + (size_t)(wave * 48 + m16) * TWOC_ + quad * 8;
    const unsigned short* ybase = xt + ((size_t)b * N_ + n0 + m16) * C_ + quad * 8;

    floatx4 acc[3][2];
#pragma unroll
    for (int i = 0; i < 3; i++)
#pragma unroll
        for (int j = 0; j < 2; j++) acc[i][j] = (floatx4){0.f, 0.f, 0.f, 0.f};

    // xs half: W cols 0..191, y from global xt
#pragma unroll 2
    for (int kt = 0; kt < 6; kt++) {
        half8 wf[3], yf[2];
#pragma unroll
        for (int i = 0; i < 3; i++)
            wf[i] = *(const half8*)(wbase + (size_t)(i * 16) * TWOC_ + kt * 32);
#pragma unroll
        for (int j = 0; j < 2; j++)
            yf[j] = *(const half8*)(ybase + (size_t)(j * 16) * C_ + kt * 32);
#pragma unroll
        for (int i = 0; i < 3; i++)
#pragma unroll
            for (int j = 0; j < 2; j++)
                acc[i][j] = __builtin_amdgcn_mfma_f32_16x16x32_f16(wf[i], yf[j], acc[i][j], 0, 0, 0);
    }

    // rel half: W cols 192..383, y from swizzled LDS
#pragma unroll 2
    for (int kt = 0; kt < 6; kt++) {
        half8 wf[3], yf[2];
#pragma unroll
        for (int i = 0; i < 3; i++)
            wf[i] = *(const half8*)(wbase + (size_t)(i * 16) * TWOC_ + (C_ + kt * 32));
#pragma unroll
        for (int j = 0; j < 2; j++) {
            int r = j * 16 + m16;
            yf[j] = *(const half8*)(rb0 + (size_t)r * 384 +
                                    (((unsigned)(kt * 64 + quad * 16)) ^ ((unsigned)(r & 7) << 4)));
        }
#pragma unroll
        for (int i = 0; i < 3; i++)
#pragma unroll
            for (int j = 0; j < 2; j++)
                acc[i][j] = __builtin_amdgcn_mfma_f32_16x16x32_f16(wf[i], yf[j], acc[i][j], 0, 0, 0);
    }

    // ---- epilogue: bias + ReLU, nt stores ----
#pragma unroll
    for (int i = 0; i < 3; i++) {
#pragma unroll
        for (int r = 0; r < 4; r++) {
            int o = wave * 48 + i * 16 + quad * 4 + r;
            float bv = bias[o];
#pragma unroll
            for (int j = 0; j < 2; j++) {
                int n = n0 + j * 16 + m16;
                __builtin_nontemporal_store(fmaxf(acc[i][j][r] + bv, 0.f),
                                            &out[((size_t)b * O_ + o) * N_ + n]);
            }
        }
    }
}

extern "C" void kernel_launch(void* const* d_in, const int* in_sizes, int n_in,
                              void* d_out, int out_size, void* d_ws, size_t ws_size,
                              hipStream_t stream) {
    const float* x    = (const float*)d_in[0];
    const int*   eidx = (const int*)d_in[2];
    const float* W    = (const float*)d_in[3];
    const float* bias = (const float*)d_in[4];
    float*       out  = (float*)d_out;

    unsigned short* Wb = (unsigned short*)d_ws;                     // 147456 B
    unsigned short* xt = (unsigned short*)((char*)d_ws + 147456);   // 12.58 MB

    k_prep<<<dim3(6162), dim3(256), 0, stream>>>(x, W, xt, Wb);
    k_fused<<<dim3(1024), dim3(256), 0, stream>>>(xt, eidx, Wb, bias, out);
}

// Round 5
// 138.227 us; speedup vs baseline: 1.0019x; 1.0019x over previous
//
#include <hip/hip_runtime.h>
#include <hip/hip_fp16.h>

#define B_    4
#define C_    192
#define N_    8192
#define K_    16
#define O_    192
#define TWOC_ 384
#define BN_   (B_ * N_)

typedef __attribute__((ext_vector_type(8))) _Float16 half8;
typedef __attribute__((ext_vector_type(4))) _Float16 half4v;
typedef __attribute__((ext_vector_type(4))) float floatx4;
typedef __attribute__((ext_vector_type(4))) float fvec4;
typedef __attribute__((ext_vector_type(4))) int   ivec4;
typedef __attribute__((ext_vector_type(4))) unsigned int uvec4;

static __device__ __forceinline__ half8 shflx8(half8 v, int m) {
    union { half8 h; int i[4]; } u;
    u.h = v;
#pragma unroll
    for (int q = 0; q < 4; q++) u.i[q] = __shfl_xor(u.i[q], m, 64);
    return u.h;
}
static __device__ __forceinline__ half4v shflx4(half4v v, int m) {
    union { half4v h; int i[2]; } u;
    u.h = v;
#pragma unroll
    for (int q = 0; q < 2; q++) u.i[q] = __shfl_xor(u.i[q], m, 64);
    return u.h;
}

// ---------------- K1: prep = transpose x -> xt fp16  +  convert W -> fp16 ----------------
__global__ __launch_bounds__(256) void k_prep(const float* __restrict__ x,
                                              const float* __restrict__ W,
                                              unsigned short* __restrict__ xt,
                                              unsigned short* __restrict__ Wb) {
    int bid = blockIdx.x;
    int tid = threadIdx.x;

    if (bid >= 6144) {
        int base = ((bid - 6144) * 256 + tid) * 16;
        union { unsigned short u[16]; uvec4 v[2]; } o;
#pragma unroll
        for (int q = 0; q < 16; q += 4) {
            fvec4 f = __builtin_nontemporal_load((const fvec4*)(W + base + q));
            union { _Float16 h; unsigned short s; } c;
            c.h = (_Float16)f.x; o.u[q + 0] = c.s;
            c.h = (_Float16)f.y; o.u[q + 1] = c.s;
            c.h = (_Float16)f.z; o.u[q + 2] = c.s;
            c.h = (_Float16)f.w; o.u[q + 3] = c.s;
        }
        *(uvec4*)(Wb + base)     = o.v[0];
        *(uvec4*)(Wb + base + 8) = o.v[1];
        return;
    }

    __shared__ float tile[32][33];
    int xcd  = bid & 7;
    int b    = xcd >> 1;
    int half = xcd & 1;
    int slot = bid >> 3;
    int ct   = slot >> 7;
    int nt   = half * 128 + (slot & 127);
    int c0 = ct * 32, n0 = nt * 32;

    int cc  = tid >> 3;
    int nn4 = (tid & 7) * 4;
    const float* xp = x + ((size_t)b * C_ + c0 + cc) * N_ + n0 + nn4;
    fvec4 v = __builtin_nontemporal_load((const fvec4*)xp);
    tile[nn4 + 0][cc] = v.x;
    tile[nn4 + 1][cc] = v.y;
    tile[nn4 + 2][cc] = v.z;
    tile[nn4 + 3][cc] = v.w;
    __syncthreads();

#pragma unroll
    for (int i = 0; i < 2; i++) {
        int id  = i * 256 + tid;
        int row = id >> 4;
        int ch2 = id & 15;
        union { _Float16 h[2]; unsigned int u; } p;
        p.h[0] = (_Float16)tile[row][ch2 * 2];
        p.h[1] = (_Float16)tile[row][ch2 * 2 + 1];
        *(unsigned int*)(xt + ((size_t)b * N_ + n0 + row) * C_ + c0 + ch2 * 2) = p.u;
    }
}

// ---------------- K2: fused gather + conv, deep-MLP gather ----------------
// 1024 blocks x 256 thr; block = 32 nodes. Gather: 2-node software pipeline,
// each node's 16 loads land in a dedicated named register set (~96 VGPR of
// destinations -> up to 32 outstanding loads/wave).
#define DECL_SET(S)  half8 a0##S[4], b0##S[4]; half4v a1##S[4], b1##S[4]

#define ISSUE(S, node_) {                                                     \
    int nd_ = (node_);                                                        \
    ivec4 j4 = *(const ivec4*)&sidx[nd_][kg * 4];                             \
    ivec4 i4 = *(const ivec4*)&sidx[nd_][16 + kg * 4];                        \
    _Pragma("unroll")                                                         \
    for (int it = 0; it < 4; it++) {                                          \
        const unsigned short* pj = xb + (size_t)j4[it] * C_;                  \
        const unsigned short* pi = xb + (size_t)i4[it] * C_;                  \
        a0##S[it] = *(const half8*)(pj + part * 8);                           \
        a1##S[it] = *(const half4v*)(pj + 128 + part * 4);                    \
        b0##S[it] = *(const half8*)(pi + part * 8);                           \
        b1##S[it] = *(const half4v*)(pi + 128 + part * 4);                    \
    }                                                                         \
}

#define REDUCE(S, node_) {                                                    \
    int nd_ = (node_);                                                        \
    half8  m0 = a0##S[0] - b0##S[0];                                          \
    half4v m1 = a1##S[0] - b1##S[0];                                          \
    _Pragma("unroll")                                                         \
    for (int it = 1; it < 4; it++) {                                          \
        m0 = __builtin_elementwise_max(m0, a0##S[it] - b0##S[it]);            \
        m1 = __builtin_elementwise_max(m1, a1##S[it] - b1##S[it]);            \
    }                                                                         \
    m0 = __builtin_elementwise_max(m0, shflx8(m0, 16));                       \
    m1 = __builtin_elementwise_max(m1, shflx4(m1, 16));                       \
    m0 = __builtin_elementwise_max(m0, shflx8(m0, 32));                       \
    m1 = __builtin_elementwise_max(m1, shflx4(m1, 32));                       \
    if (kg == 0) {                                                            \
        char* rb = rb0 + nd_ * 384;                                           \
        unsigned int sw = (unsigned)(nd_ & 7) << 4;                           \
        *(half8*)(rb + ((unsigned)(part * 16) ^ sw))       = m0;              \
        *(half4v*)(rb + ((unsigned)(256 + part * 8) ^ sw)) = m1;              \
    }                                                                         \
}

__global__ __launch_bounds__(256, 3) void k_fused(const unsigned short* __restrict__ xt,
                                                  const int* __restrict__ eidx,
                                                  const unsigned short* __restrict__ Wb,
                                                  const float* __restrict__ bias,
                                                  float* __restrict__ out) {
    __shared__ __align__(16) unsigned short rtile[32 * C_];   // 12 KiB
    __shared__ __align__(16) int sidx[32][36];                // 4.5 KiB
    char* rb0 = (char*)rtile;

    int bid  = blockIdx.x;               // 1024
    int xcd  = bid & 7;
    int b    = xcd >> 1;
    int slot = bid >> 3;                 // 0..127
    int n0   = ((xcd & 1) * 128 + slot) * 32;

    int tid  = threadIdx.x;
    int wave = tid >> 6;
    int lane = tid & 63;
    int m16  = lane & 15;
    int quad = lane >> 4;

    // ---- stage sidx ----
    {
        const int* e0 = eidx + ((size_t)b * N_ + n0) * K_;
        const int* e1 = e0 + (size_t)BN_ * K_;
        int side = tid >> 7;
        int id   = tid & 127;
        const int* src = side ? e1 : e0;
        ivec4 v = __builtin_nontemporal_load((const ivec4*)src + id);
        int node = id >> 2, kq = (id & 3) * 4;
        *(ivec4*)&sidx[node][side * 16 + kq] = v;
    }
    __syncthreads();

    // ---- gather: 2-node pipelined, full-MLP ----
    {
        int kg = quad, part = m16;
        const unsigned short* xb = xt + (size_t)b * N_ * C_;
        int base = wave * 8;
        DECL_SET(A);
        DECL_SET(B);
        ISSUE(A, base + 0);
        ISSUE(B, base + 1);
        REDUCE(A, base + 0);
        ISSUE(A, base + 2);
        REDUCE(B, base + 1);
        ISSUE(B, base + 3);
        REDUCE(A, base + 2);
        ISSUE(A, base + 4);
        REDUCE(B, base + 3);
        ISSUE(B, base + 5);
        REDUCE(A, base + 4);
        ISSUE(A, base + 6);
        REDUCE(B, base + 5);
        ISSUE(B, base + 7);
        REDUCE(A, base + 6);
        REDUCE(B, base + 7);
    }
    __syncthreads();

    // ---- GEMM: wave = o-block [wave*48, wave*48+48), n = 32 ----
    const unsigned short* wbase = Wb + (size_t)(wave * 48 + m16) * TWOC_ + quad * 8;
    const unsigned short* ybase = xt + ((size_t)b * N_ + n0 + m16) * C_ + quad * 8;

    floatx4 acc[3][2];
#pragma unroll
    for (int i = 0; i < 3; i++)
#pragma unroll
        for (int j = 0; j < 2; j++) acc[i][j] = (floatx4){0.f, 0.f, 0.f, 0.f};

    // xs half: W cols 0..191, y from global xt
#pragma unroll 2
    for (int kt = 0; kt < 6; kt++) {
        half8 wf[3], yf[2];
#pragma unroll
        for (int i = 0; i < 3; i++)
            wf[i] = *(const half8*)(wbase + (size_t)(i * 16) * TWOC_ + kt * 32);
#pragma unroll
        for (int j = 0; j < 2; j++)
            yf[j] = *(const half8*)(ybase + (size_t)(j * 16) * C_ + kt * 32);
#pragma unroll
        for (int i = 0; i < 3; i++)
#pragma unroll
            for (int j = 0; j < 2; j++)
                acc[i][j] = __builtin_amdgcn_mfma_f32_16x16x32_f16(wf[i], yf[j], acc[i][j], 0, 0, 0);
    }

    // rel half: W cols 192..383, y from swizzled LDS
#pragma unroll 2
    for (int kt = 0; kt < 6; kt++) {
        half8 wf[3], yf[2];
#pragma unroll
        for (int i = 0; i < 3; i++)
            wf[i] = *(const half8*)(wbase + (size_t)(i * 16) * TWOC_ + (C_ + kt * 32));
#pragma unroll
        for (int j = 0; j < 2; j++) {
            int r = j * 16 + m16;
            yf[j] = *(const half8*)(rb0 + (size_t)r * 384 +
                                    (((unsigned)(kt * 64 + quad * 16)) ^ ((unsigned)(r & 7) << 4)));
        }
#pragma unroll
        for (int i = 0; i < 3; i++)
#pragma unroll
            for (int j = 0; j < 2; j++)
                acc[i][j] = __builtin_amdgcn_mfma_f32_16x16x32_f16(wf[i], yf[j], acc[i][j], 0, 0, 0);
    }

    // ---- epilogue: bias + ReLU, nt stores ----
#pragma unroll
    for (int i = 0; i < 3; i++) {
#pragma unroll
        for (int r = 0; r < 4; r++) {
            int o = wave * 48 + i * 16 + quad * 4 + r;
            float bv = bias[o];
#pragma unroll
            for (int j = 0; j < 2; j++) {
                int n = n0 + j * 16 + m16;
                __builtin_nontemporal_store(fmaxf(acc[i][j][r] + bv, 0.f),
                                            &out[((size_t)b * O_ + o) * N_ + n]);
            }
        }
    }
}

extern "C" void kernel_launch(void* const* d_in, const int* in_sizes, int n_in,
                              void* d_out, int out_size, void* d_ws, size_t ws_size,
                              hipStream_t stream) {
    const float* x    = (const float*)d_in[0];
    const int*   eidx = (const int*)d_in[2];
    const float* W    = (const float*)d_in[3];
    const float* bias = (const float*)d_in[4];
    float*       out  = (float*)d_out;

    unsigned short* Wb = (unsigned short*)d_ws;                     // 147456 B
    unsigned short* xt = (unsigned short*)((char*)d_ws + 147456);   // 12.58 MB

    k_prep<<<dim3(6162), dim3(256), 0, stream>>>(x, W, xt, Wb);
    k_fused<<<dim3(1024), dim3(256), 0, stream>>>(xt, eidx, Wb, bias, out);
}